// Round 4
// baseline (404.592 us; speedup 1.0000x reference)
//
#include <hip/hip_runtime.h>
#include <math.h>

// ---- problem constants ----
#define B   64
#define L   64
#define C   16
#define CHD 64
#define EMB 300
#define D   450       // EMB + 3*50
#define DP  480       // padded bf16 row stride
#define NT  (B*L)     // 4096 tokens per branch
#define NBH 128       // 2 branches * 64 batch

typedef short bf16x8 __attribute__((ext_vector_type(8)));
typedef float f32x4  __attribute__((ext_vector_type(4)));
typedef float f32x2  __attribute__((ext_vector_type(2)));
typedef unsigned short ushort_t;
typedef ushort_t us4 __attribute__((ext_vector_type(4)));

#define MFMA16 __builtin_amdgcn_mfma_f32_16x16x32_bf16

// ---------------- helpers ----------------
__device__ inline float wave_sum(float v) {
#pragma unroll
    for (int o = 32; o; o >>= 1) v += __shfl_xor(v, o, 64);
    return v;
}
__device__ inline ushort_t f2b(float f) {   // RNE float->bf16
    union { float f; unsigned u; } c; c.f = f;
    unsigned r = c.u + 0x7FFFu + ((c.u >> 16) & 1u);
    return (ushort_t)(r >> 16);
}

// ---------------- kernel P: fused weight prep ----------------
__global__ __launch_bounds__(256) void prep_kernel(
    const float* __restrict__ W,                                 // highway weight
    const float* __restrict__ w3, const float* __restrict__ b3,
    const float* __restrict__ w4, const float* __restrict__ b4,
    const float* __restrict__ w5, const float* __restrict__ b5,
    const float* __restrict__ char_emb,
    ushort_t* __restrict__ Wb16,
    ushort_t* __restrict__ Wpad, float* __restrict__ bias160,
    ushort_t* __restrict__ ceb16)
{
    int idx = blockIdx.x * 256 + threadIdx.x;
    if (idx < 512 * DP) {
        int n = idx / DP, k = idx - n * DP;
        float v = (n < D && k < D) ? W[(size_t)n * D + k] : 0.f;
        Wb16[idx] = f2b(v);
        return;
    }
    idx -= 512 * DP;
    if (idx < 160 * 320) {
        int f = idx / 320, kd = idx - f * 320;
        int k = kd >> 6, d = kd & 63;
        float v = 0.f;
        if (f < 50)       { if (k < 3) v = w3[f * 192 + d * 3 + k]; }
        else if (f < 100) { if (k < 4) v = w4[(f - 50) * 256 + d * 4 + k]; }
        else if (f < 150) { v = w5[(f - 100) * 320 + d * 5 + k]; }
        Wpad[idx] = f2b(v);
    } else if (idx < 160 * 320 + 160) {
        int f = idx - 160 * 320;
        bias160[f] = (f < 50) ? b3[f] : (f < 100) ? b4[f - 50] : (f < 150) ? b5[f - 100] : 0.f;
    } else if (idx < 160 * 320 + 160 + 100 * 64) {
        int i = idx - (160 * 320 + 160);
        ceb16[i] = f2b(char_emb[i]);
    }
}

// ---------------- kernel 1: fused word-embed copy + char conv ----------------
#define ESS 72
#define EST (20 * ESS)

__global__ __launch_bounds__(256) void embed_conv_kernel(
    const int* __restrict__ q1, const int* __restrict__ q2,
    const int* __restrict__ q1c, const int* __restrict__ q2c,
    const float* __restrict__ word_emb, const ushort_t* __restrict__ ceb16,
    const ushort_t* __restrict__ Wpad, const float* __restrict__ bias160,
    float* __restrict__ xout, ushort_t* __restrict__ xb16)
{
    __shared__ ushort_t es[8 * EST];   // 23040 B

    const int tid  = threadIdx.x;
    const int wv   = tid >> 6;
    const int lane = tid & 63;
    const int ln   = lane & 15, quad = lane >> 4;
    const int bx   = blockIdx.x;
    const int tokbase = ((bx & 7) * 128 + (bx >> 3)) * 8;

    // ---- stage char-embedding rows for 8 tokens (gather by char id) ----
#pragma unroll
    for (int i = 0; i < 4; ++i) {
        int c = tid + i * 256;
        int row = c >> 3, part = c & 7;
        int tl = row >> 4, cr = row & 15;
        int gtok   = tokbase + tl;
        int branch = gtok >> 12;
        int tokl   = gtok & (NT - 1);
        int cid    = (branch ? q2c : q1c)[tokl * C + cr];
        *(bf16x8*)&es[tl * EST + cr * ESS + part * 8] =
            *(const bf16x8*)&ceb16[cid * 64 + part * 8];
    }
    {   // zero the 4 pad rows per token
        int tl = tid >> 5, rr = (tid >> 3) & 3, part = tid & 7;
        bf16x8 z = {0, 0, 0, 0, 0, 0, 0, 0};
        *(bf16x8*)&es[tl * EST + (16 + rr) * ESS + part * 8] = z;
    }

    // ---- word-embedding copy for the same 8 tokens ----
#pragma unroll 1
    for (int c = tid; c < 8 * 75; c += 256) {
        const int t  = c / 75, d4 = c - t * 75;
        const int tok    = tokbase + t;
        const int branch = tok >> 12;
        const int tokl   = tok & (NT - 1);
        const int w      = (branch ? q2 : q1)[tokl];
        const float4 v = *(const float4*)(word_emb + (size_t)w * EMB + d4 * 4);
        float* dst = xout + (size_t)tok * D + d4 * 4;
        *(f32x2*)dst       = (f32x2){v.x, v.y};
        *(f32x2*)(dst + 2) = (f32x2){v.z, v.w};
        us4 pk = { f2b(v.x), f2b(v.y), f2b(v.z), f2b(v.w) };
        *(us4*)(xb16 + (size_t)tok * DP + d4 * 4) = pk;
    }
    if (tid < 240) {   // zero-pad D..DP for 8 tokens
        const int t = tid / 30, k = tid - t * 30;
        xb16[(size_t)(tokbase + t) * DP + D + k] = 0;
    }
    __syncthreads();

    // ---- conv via MFMA ----
    const int t0 = wv * 2, t1 = t0 + 1;
    f32x4 acc[2][10];
#pragma unroll
    for (int t = 0; t < 2; ++t)
#pragma unroll
        for (int nt = 0; nt < 10; ++nt) acc[t][nt] = (f32x4){0.f, 0.f, 0.f, 0.f};

#pragma unroll 1
    for (int ks = 0; ks < 10; ++ks) {
        const int kk   = ks * 32 + quad * 8;
        const int arow = kk >> 6, aoff = kk & 63;
        bf16x8 a0 = *(const bf16x8*)&es[t0 * EST + (ln + arow) * ESS + aoff];
        bf16x8 a1 = *(const bf16x8*)&es[t1 * EST + (ln + arow) * ESS + aoff];
#pragma unroll
        for (int nt = 0; nt < 10; ++nt) {
            bf16x8 bf = *(const bf16x8*)&Wpad[(size_t)(nt * 16 + ln) * 320 + kk];
            acc[0][nt] = MFMA16(a0, bf, acc[0][nt], 0, 0, 0);
            acc[1][nt] = MFMA16(a1, bf, acc[1][nt], 0, 0, 0);
        }
    }

#pragma unroll
    for (int t = 0; t < 2; ++t) {
        const int gtok = tokbase + t0 + t;
#pragma unroll
        for (int nt = 0; nt < 10; ++nt) {
            const int f  = nt * 16 + ln;
            const int Pf = (f < 50) ? 14 : (f < 100) ? 13 : 12;
            float m = -1e30f;
#pragma unroll
            for (int r = 0; r < 4; ++r) {
                const int p = quad * 4 + r;
                if (p < Pf) m = fmaxf(m, acc[t][nt][r]);
            }
            m = fmaxf(m, __shfl_xor(m, 16, 64));
            m = fmaxf(m, __shfl_xor(m, 32, 64));
            if (quad == 0 && f < 150) {
                float rv = fmaxf(0.f, m + bias160[f]);
                xout[(size_t)gtok * D + EMB + f] = rv;
                xb16[(size_t)gtok * DP + EMB + f] = f2b(rv);
            }
        }
    }
}

// ---------------- kernel 2: fused highway x2 + attn x2, one block per bh ----------------
// 128 blocks x 1024 threads (16 waves). X (bf16) lives in LDS for the whole stack.
// LDS: Xb 62464 + R 79872 (xw3+sc, overlaid later by XT) + Al 9216 + s1s/s2s 512 = 152064 B.
#define XBS 488   // Xb / xw3 LDS row stride (bf16): 2-way-max bank aliasing on A-reads
#define XTS 72    // X^T LDS row stride
#define ALS 72    // P LDS row stride

__global__ __launch_bounds__(1024) void fused_stack_kernel(
    const ushort_t* __restrict__ xb16a,
    float* __restrict__ buf0, float* __restrict__ buf1,
    const ushort_t* __restrict__ Wb16, const float* __restrict__ hw_b,
    const float* __restrict__ attn_w, const float* __restrict__ attn_b,
    const int* __restrict__ q1_len, const int* __restrict__ q2_len,
    float* __restrict__ out)
{
    __shared__ __align__(16) ushort_t Xb[64 * XBS];   // 62464 B
    __shared__ __align__(16) ushort_t Rb[39936];      // 79872 B (xw3 62464 | sc 17408; XT 69120 overlay)
    __shared__ __align__(16) ushort_t Al[64 * ALS];   // 9216 B
    __shared__ float s1s[64], s2s[64];

    ushort_t* xw3L = Rb;                       // [64][XBS] bf16
    float*    sc   = (float*)(Rb + 31232);     // [64][68] f32 at byte 62464
    ushort_t* XT   = Rb;                       // [480][XTS] bf16 (after sc/xw3 dead)

    const int bh     = blockIdx.x;
    const int branch = bh >> 6, bb = bh & 63;
    const int tid  = threadIdx.x;
    const int wv   = tid >> 6;                 // 0..15
    const int lane = tid & 63;
    const int ln   = lane & 15, quad = lane >> 4;

    // ---- stage Xb from global bf16 mirror ----
    {
        const ushort_t* xbb = xb16a + (size_t)bh * 64 * DP;
#pragma unroll 1
        for (int c = tid; c < 64 * 60; c += 1024) {
            const int j = c / 60, k8 = c - j * 60;
            *(bf16x8*)&Xb[j * XBS + k8 * 8] = *(const bf16x8*)&xbb[(size_t)j * DP + k8 * 8];
        }
    }
    __syncthreads();

    // ================= highway x2 =================
    const int msB = (wv >> 3) * 2;   // m-strips {msB, msB+1}
    const int ng  = wv & 7;          // n-tiles ng*4 .. ng*4+3 (<30)
#pragma unroll 1
    for (int h = 0; h < 2; ++h) {
        const float* xin  = (h == 0 ? buf0 : buf1) + (size_t)bh * 64 * D;
        float*       xout = (h == 0 ? buf1 : buf0) + (size_t)bh * 64 * D;

        f32x4 acc[2][4];
#pragma unroll
        for (int i = 0; i < 2; ++i)
#pragma unroll
            for (int t = 0; t < 4; ++t) acc[i][t] = (f32x4){0.f, 0.f, 0.f, 0.f};

#pragma unroll 1
        for (int k0 = 0; k0 < DP; k0 += 32) {
            bf16x8 a0 = *(const bf16x8*)&Xb[(msB * 16 + ln) * XBS + quad * 8 + k0];
            bf16x8 a1 = *(const bf16x8*)&Xb[((msB + 1) * 16 + ln) * XBS + quad * 8 + k0];
#pragma unroll
            for (int t = 0; t < 4; ++t) {
                const int nt = ng * 4 + t;
                if (nt < 30) {
                    bf16x8 bf = *(const bf16x8*)&Wb16[(size_t)(nt * 16 + ln) * DP + quad * 8 + k0];
                    acc[0][t] = MFMA16(a0, bf, acc[0][t], 0, 0, 0);
                    acc[1][t] = MFMA16(a1, bf, acc[1][t], 0, 0, 0);
                }
            }
        }
        __syncthreads();   // all Xb reads done before overwrite

#pragma unroll
        for (int t = 0; t < 4; ++t) {
            const int nt = ng * 4 + t;
            if (nt >= 30) continue;
            const int n = nt * 16 + ln;
            const bool nval = (n < D);
            const float bv = nval ? hw_b[n] : 0.f;
#pragma unroll
            for (int mi = 0; mi < 2; ++mi) {
#pragma unroll
                for (int reg = 0; reg < 4; ++reg) {
                    const int m = (msB + mi) * 16 + quad * 4 + reg;
                    float y = acc[mi][t][reg] + bv;
                    float g = 1.f / (1.f + __expf(-y));
                    float o = 0.f;
                    if (nval) {
                        float xo = xin[(size_t)m * D + n];
                        o = g * fmaxf(y, 0.f) + (1.f - g) * xo;
                        xout[(size_t)m * D + n] = o;
                    }
                    Xb[m * XBS + n] = f2b(nval ? o : 0.f);
                }
            }
        }
        __syncthreads();
    }

    // ================= attention x2 =================
    const int len = (branch ? q2_len : q1_len)[bb];
#pragma unroll 1
    for (int a = 0; a < 2; ++a) {
        const float* xin = (a == 0 ? buf0 : buf1) + (size_t)bh * 64 * D;
        const float* wb  = attn_w + (size_t)a * 3 * D;   // w1 | w2 | w3
        const float* w3  = wb + 2 * D;
        const float bias = attn_b[a];

        // ---- xw3 = f2b(x * w3) into LDS ----
#pragma unroll 1
        for (int c = tid; c < 64 * 60; c += 1024) {
            const int j = c / 60, k8 = c - j * 60, k0 = k8 * 8;
            const float* xr = xin + (size_t)j * D;
            bf16x8 pk;
#pragma unroll
            for (int t = 0; t < 8; ++t) {
                const int k = k0 + t;
                float p = (k < D) ? xr[k] * w3[k] : 0.f;
                pk[t] = (short)f2b(p);
            }
            *(bf16x8*)&xw3L[j * XBS + k0] = pk;
        }
        // ---- s1/s2 dots (8 per wave) ----
#pragma unroll 1
        for (int rr = 0; rr < 8; ++rr) {
            const int p = wv * 8 + rr;
            const int row = p & 63;
            const float* wsel = (p < 64) ? wb : (wb + D);
            const float* xr = xin + (size_t)row * D;
            float s = 0.f;
#pragma unroll
            for (int t = 0; t < 8; ++t) {
                const int k = lane + t * 64;
                if (k < D) s = fmaf(xr[k], wsel[k], s);
            }
            s = wave_sum(s);
            if (lane == 0) { if (p < 64) s1s[row] = s; else s2s[row] = s; }
        }
        __syncthreads();

        // ---- QK^T: wave = (it, jt) tile of the 64x64 score matrix ----
        {
            const int it = wv >> 2, jt = wv & 3;
            const ushort_t* xa = &Xb[(it * 16 + ln) * XBS + quad * 8];
            const ushort_t* xb = &xw3L[(jt * 16 + ln) * XBS + quad * 8];
            f32x4 qa0 = (f32x4){0.f, 0.f, 0.f, 0.f};
            f32x4 qa1 = (f32x4){0.f, 0.f, 0.f, 0.f};
#pragma unroll
            for (int ks = 0; ks < 14; ks += 2) {
                bf16x8 a0 = *(const bf16x8*)(xa + ks * 32);
                bf16x8 b0 = *(const bf16x8*)(xb + ks * 32);
                bf16x8 a1 = *(const bf16x8*)(xa + ks * 32 + 32);
                bf16x8 b1 = *(const bf16x8*)(xb + ks * 32 + 32);
                qa0 = MFMA16(a0, b0, qa0, 0, 0, 0);
                qa1 = MFMA16(a1, b1, qa1, 0, 0, 0);
            }
            {
                bf16x8 at = *(const bf16x8*)(xa + 14 * 32);
                bf16x8 bt = *(const bf16x8*)(xb + 14 * 32);
                qa0 = MFMA16(at, bt, qa0, 0, 0, 0);
            }
            f32x4 qacc = qa0 + qa1;
            const int j = jt * 16 + ln;
            const float s2v = s2s[j];
#pragma unroll
            for (int reg = 0; reg < 4; ++reg) {
                const int i = it * 16 + quad * 4 + reg;
                float v = qacc[reg] + s1s[i] + s2v + bias;
                if (j >= len) v = -1e-9f;        // reference's (buggy) mask value
                sc[i * 68 + j] = v;
            }
        }
        __syncthreads();

        // ---- softmax: 4 rows per wave ----
#pragma unroll
        for (int rr = 0; rr < 4; ++rr) {
            const int r = wv * 4 + rr;
            float v = sc[r * 68 + lane];
            float m = v;
#pragma unroll
            for (int o = 32; o; o >>= 1) m = fmaxf(m, __shfl_xor(m, o, 64));
            float ev = __expf(v - m);
            float sm = ev;
#pragma unroll
            for (int o = 32; o; o >>= 1) sm += __shfl_xor(sm, o, 64);
            Al[r * ALS + lane] = f2b(ev * (1.f / sm));
        }
        __syncthreads();

        // ---- XT build (Xb -> XT, packed u32; overlays dead xw3/sc) ----
#pragma unroll 1
        for (int c = tid; c < 240 * 32; c += 1024) {
            const int d2 = c >> 5, jp = (c & 31) * 2;
            unsigned r0 = *(const unsigned*)&Xb[jp * XBS + d2 * 2];
            unsigned r1 = *(const unsigned*)&Xb[(jp + 1) * XBS + d2 * 2];
            unsigned lo = (r0 & 0xFFFFu) | (r1 << 16);
            unsigned hi = (r0 >> 16) | (r1 & 0xFFFF0000u);
            *(unsigned*)&XT[(d2 * 2) * XTS + jp]     = lo;
            *(unsigned*)&XT[(d2 * 2 + 1) * XTS + jp] = hi;
        }
        __syncthreads();

        // ---- AV: wave = (i-strip, d-group of 8 tiles) ----
        {
            const int ita = wv & 3, dg = wv >> 2;
            bf16x8 af0 = *(const bf16x8*)&Al[(ita * 16 + ln) * ALS + quad * 8];
            bf16x8 af1 = *(const bf16x8*)&Al[(ita * 16 + ln) * ALS + quad * 8 + 32];
            float* outp = (a == 0) ? (buf1 + (size_t)bh * 64 * D)
                                   : (out  + (size_t)bh * 64 * D);
#pragma unroll 2
            for (int t = 0; t < 8; ++t) {
                const int dt = dg * 8 + t;
                if (dt < 30) {
                    bf16x8 b0 = *(const bf16x8*)&XT[(dt * 16 + ln) * XTS + quad * 8];
                    bf16x8 b1 = *(const bf16x8*)&XT[(dt * 16 + ln) * XTS + quad * 8 + 32];
                    f32x4 acc = (f32x4){0.f, 0.f, 0.f, 0.f};
                    acc = MFMA16(af0, b0, acc, 0, 0, 0);
                    acc = MFMA16(af1, b1, acc, 0, 0, 0);
                    const int d = dt * 16 + ln;
                    if (d < D) {
#pragma unroll
                        for (int reg = 0; reg < 4; ++reg) {
                            const int i = ita * 16 + quad * 4 + reg;
                            float v = acc[reg];
                            if (a == 0) v += xin[(size_t)i * D + d];
                            outp[(size_t)i * D + d] = v;
                            if (a == 0) Xb[i * XBS + d] = f2b(v);
                        }
                    }
                }
            }
        }
        __syncthreads();
    }
}

// ---------------- launch ----------------
extern "C" void kernel_launch(void* const* d_in, const int* in_sizes, int n_in,
                              void* d_out, int out_size, void* d_ws, size_t ws_size,
                              hipStream_t stream) {
    const int*   q1       = (const int*)  d_in[0];
    const int*   q2       = (const int*)  d_in[1];
    const int*   q1_len   = (const int*)  d_in[2];
    const int*   q2_len   = (const int*)  d_in[3];
    const int*   q1c      = (const int*)  d_in[4];
    const int*   q2c      = (const int*)  d_in[5];
    const float* word_emb = (const float*)d_in[6];
    const float* char_emb = (const float*)d_in[7];
    const float* w3       = (const float*)d_in[8];
    const float* b3       = (const float*)d_in[9];
    const float* w4       = (const float*)d_in[10];
    const float* b4       = (const float*)d_in[11];
    const float* w5       = (const float*)d_in[12];
    const float* b5       = (const float*)d_in[13];
    const float* hw_w     = (const float*)d_in[14];
    const float* hw_b     = (const float*)d_in[15];
    const float* attn_w   = (const float*)d_in[16];
    const float* attn_b   = (const float*)d_in[17];
    float* out = (float*)d_out;

    float*    buf0    = (float*)d_ws;                          // 2*NT*D f32
    float*    buf1    = buf0 + (size_t)2 * NT * D;             // 2*NT*D f32
    float*    bias160 = buf1 + (size_t)2 * NT * D;             // 160 f32
    ushort_t* xb16a   = (ushort_t*)(bias160 + 160);            // 2*NT*DP bf16
    ushort_t* xb16b   = xb16a + (size_t)2 * NT * DP;           // (unused, kept for layout)
    ushort_t* Wb16    = xb16b + (size_t)2 * NT * DP;           // 512*DP bf16
    ushort_t* Wpad    = Wb16 + (size_t)512 * DP;               // 160*320 bf16
    ushort_t* ceb16   = Wpad + (size_t)160 * 320;              // 100*64 bf16

    // 1. weight prep + fused embed/conv -> buf0 f32 + xb16a
    prep_kernel<<<(512 * DP + 160 * 320 + 160 + 100 * 64 + 255) / 256, 256, 0, stream>>>(
        hw_w, w3, b3, w4, b4, w5, b5, char_emb, Wb16, Wpad, bias160, ceb16);
    embed_conv_kernel<<<1024, 256, 0, stream>>>(q1, q2, q1c, q2c, word_emb, ceb16,
                                                Wpad, bias160, buf0, xb16a);

    // 2. the whole rest of the model in one kernel: highway x2 + attn x2
    fused_stack_kernel<<<NBH, 1024, 0, stream>>>(
        xb16a, buf0, buf1, Wb16, hw_b, attn_w, attn_b, q1_len, q2_len, out);
}

// Round 5
// 339.762 us; speedup vs baseline: 1.1908x; 1.1908x over previous
//
#include <hip/hip_runtime.h>
#include <math.h>

// ---- problem constants ----
#define B   64
#define L   64
#define C   16
#define CHD 64
#define EMB 300
#define D   450       // EMB + 3*50
#define DP  480       // padded bf16 row stride
#define NT  (B*L)     // 4096 tokens per branch
#define NBH 128       // 2 branches * 64 batch

typedef short bf16x8 __attribute__((ext_vector_type(8)));
typedef float f32x4  __attribute__((ext_vector_type(4)));
typedef float f32x2  __attribute__((ext_vector_type(2)));
typedef unsigned short ushort_t;
typedef ushort_t us4 __attribute__((ext_vector_type(4)));

#define MFMA16 __builtin_amdgcn_mfma_f32_16x16x32_bf16

// fragment-major sizes
#define WPF_N (10 * 10 * 512)           // WpadF: 10 nt x 10 ks x 64 lane x 8
#define WBF_N (32 * 15 * 512)           // Wb16F: 32 nt x 15 ks x 64 lane x 8
#define XFRAG 30720                     // per-bh fragment image: 4|30 tiles x 15|2 ks x 512

// ---------------- helpers ----------------
__device__ inline float wave_sum(float v) {
#pragma unroll
    for (int o = 32; o; o >>= 1) v += __shfl_xor(v, o, 64);
    return v;
}
__device__ inline ushort_t f2b(float f) {   // RNE float->bf16
    union { float f; unsigned u; } c; c.f = f;
    unsigned r = c.u + 0x7FFFu + ((c.u >> 16) & 1u);
    return (ushort_t)(r >> 16);
}

// ---------------- kernel P: fused weight prep (fragment-major images) ----------------
__global__ __launch_bounds__(256) void prep_kernel(
    const float* __restrict__ W,                                 // highway weight
    const float* __restrict__ w3, const float* __restrict__ b3,
    const float* __restrict__ w4, const float* __restrict__ b4,
    const float* __restrict__ w5, const float* __restrict__ b5,
    const float* __restrict__ char_emb,
    ushort_t* __restrict__ Wb16F, ushort_t* __restrict__ WpadF,
    float* __restrict__ bias160, ushort_t* __restrict__ ceb16)
{
    int idx = blockIdx.x * 256 + threadIdx.x;
    if (idx < WBF_N) {   // highway weight fragments
        const int e = idx & 7, l = (idx >> 3) & 63, t = idx >> 9;
        const int ks = t % 15, nt = t / 15;
        const int ln = l & 15, q = l >> 4;
        const int n = nt * 16 + ln, k = ks * 32 + q * 8 + e;
        float v = (n < D && k < D) ? W[(size_t)n * D + k] : 0.f;
        Wb16F[idx] = f2b(v);
        return;
    }
    idx -= WBF_N;
    if (idx < WPF_N) {   // conv weight fragments
        const int e = idx & 7, l = (idx >> 3) & 63, t = idx >> 9;
        const int ks = t % 10, nt = t / 10;
        const int ln = l & 15, q = l >> 4;
        const int f = nt * 16 + ln;
        const int kd = ks * 32 + q * 8 + e;
        const int k = kd >> 6, d = kd & 63;
        float v = 0.f;
        if (f < 50)       { if (k < 3) v = w3[f * 192 + d * 3 + k]; }
        else if (f < 100) { if (k < 4) v = w4[(f - 50) * 256 + d * 4 + k]; }
        else if (f < 150) { v = w5[(f - 100) * 320 + d * 5 + k]; }
        WpadF[idx] = f2b(v);
        return;
    }
    idx -= WPF_N;
    if (idx < 160) {
        bias160[idx] = (idx < 50) ? b3[idx] : (idx < 100) ? b4[idx - 50]
                     : (idx < 150) ? b5[idx - 100] : 0.f;
    } else if (idx < 160 + 100 * 64) {
        int i = idx - 160;
        ceb16[i] = f2b(char_emb[i]);
    }
}

// ---------------- kernel 1: fused word-embed copy + char conv ----------------
#define ESS 72
#define EST (20 * ESS)

__global__ __launch_bounds__(256) void embed_conv_kernel(
    const int* __restrict__ q1, const int* __restrict__ q2,
    const int* __restrict__ q1c, const int* __restrict__ q2c,
    const float* __restrict__ word_emb, const ushort_t* __restrict__ ceb16,
    const ushort_t* __restrict__ WpadF, const float* __restrict__ bias160,
    float* __restrict__ xout, ushort_t* __restrict__ xb16)
{
    __shared__ ushort_t es[8 * EST];   // 23040 B (reused as f32 staging in epilogue)

    const int tid  = threadIdx.x;
    const int wv   = tid >> 6;
    const int lane = tid & 63;
    const int ln   = lane & 15, quad = lane >> 4;
    const int bx   = blockIdx.x;
    const int tokbase = ((bx & 7) * 128 + (bx >> 3)) * 8;

    // ---- stage char-embedding rows for 8 tokens (gather by char id) ----
#pragma unroll
    for (int i = 0; i < 4; ++i) {
        int c = tid + i * 256;
        int row = c >> 3, part = c & 7;
        int tl = row >> 4, cr = row & 15;
        int gtok   = tokbase + tl;
        int branch = gtok >> 12;
        int tokl   = gtok & (NT - 1);
        int cid    = (branch ? q2c : q1c)[tokl * C + cr];
        *(bf16x8*)&es[tl * EST + cr * ESS + part * 8] =
            *(const bf16x8*)&ceb16[cid * 64 + part * 8];
    }
    {   // zero the 4 pad rows per token
        int tl = tid >> 5, rr = (tid >> 3) & 3, part = tid & 7;
        bf16x8 z = {0, 0, 0, 0, 0, 0, 0, 0};
        *(bf16x8*)&es[tl * EST + (16 + rr) * ESS + part * 8] = z;
    }

    // ---- word-embedding copy for the same 8 tokens ----
#pragma unroll 1
    for (int c = tid; c < 8 * 75; c += 256) {
        const int t  = c / 75, d4 = c - t * 75;
        const int tok    = tokbase + t;
        const int branch = tok >> 12;
        const int tokl   = tok & (NT - 1);
        const int w      = (branch ? q2 : q1)[tokl];
        const float4 v = *(const float4*)(word_emb + (size_t)w * EMB + d4 * 4);
        float* dst = xout + (size_t)tok * D + d4 * 4;
        *(f32x2*)dst       = (f32x2){v.x, v.y};
        *(f32x2*)(dst + 2) = (f32x2){v.z, v.w};
        us4 pk = { f2b(v.x), f2b(v.y), f2b(v.z), f2b(v.w) };
        *(us4*)(xb16 + (size_t)tok * DP + d4 * 4) = pk;
    }
    if (tid < 240) {   // zero-pad D..DP for 8 tokens
        const int t = tid / 30, k = tid - t * 30;
        xb16[(size_t)(tokbase + t) * DP + D + k] = 0;
    }
    __syncthreads();

    // ---- conv via MFMA (B fragments coalesced from WpadF) ----
    const int t0 = wv * 2, t1 = t0 + 1;
    f32x4 acc[2][10];
#pragma unroll
    for (int t = 0; t < 2; ++t)
#pragma unroll
        for (int nt = 0; nt < 10; ++nt) acc[t][nt] = (f32x4){0.f, 0.f, 0.f, 0.f};

#pragma unroll 1
    for (int ks = 0; ks < 10; ++ks) {
        const int kk   = ks * 32 + quad * 8;
        const int arow = kk >> 6, aoff = kk & 63;
        bf16x8 a0 = *(const bf16x8*)&es[t0 * EST + (ln + arow) * ESS + aoff];
        bf16x8 a1 = *(const bf16x8*)&es[t1 * EST + (ln + arow) * ESS + aoff];
#pragma unroll
        for (int nt = 0; nt < 10; ++nt) {
            bf16x8 bf = *(const bf16x8*)&WpadF[(size_t)((nt * 10 + ks) << 9) + lane * 8];
            acc[0][nt] = MFMA16(a0, bf, acc[0][nt], 0, 0, 0);
            acc[1][nt] = MFMA16(a1, bf, acc[1][nt], 0, 0, 0);
        }
    }
    __syncthreads();   // es reads done; reuse as f32 staging

    // ---- epilogue: reduce + stage in LDS, then coalesced emit ----
    float* smf = (float*)es;   // [8][160] f32
#pragma unroll
    for (int t = 0; t < 2; ++t) {
        const int tloc = t0 + t;
#pragma unroll
        for (int nt = 0; nt < 10; ++nt) {
            const int f  = nt * 16 + ln;
            const int Pf = (f < 50) ? 14 : (f < 100) ? 13 : 12;
            float m = -1e30f;
#pragma unroll
            for (int r = 0; r < 4; ++r) {
                const int p = quad * 4 + r;
                if (p < Pf) m = fmaxf(m, acc[t][nt][r]);
            }
            m = fmaxf(m, __shfl_xor(m, 16, 64));
            m = fmaxf(m, __shfl_xor(m, 32, 64));
            if (quad == 0) smf[tloc * 160 + f] = fmaxf(0.f, m + bias160[f]);
        }
    }
    __syncthreads();
#pragma unroll 1
    for (int c = tid; c < 8 * 150; c += 256) {
        const int t = c / 150, f = c - t * 150;
        const float rv = smf[t * 160 + f];
        xout[(size_t)(tokbase + t) * D + EMB + f] = rv;
        xb16[(size_t)(tokbase + t) * DP + EMB + f] = f2b(rv);
    }
}

// ---------------- kernel 2: highway via bf16 MFMA (coalesced B, XCD-affine grid) ----------------
__global__ __launch_bounds__(256, 4) void highway_mfma_kernel(
    const ushort_t* __restrict__ xb16, const float* __restrict__ xf32,
    const ushort_t* __restrict__ Wb16F, const float* __restrict__ bvec,
    float* __restrict__ out, ushort_t* __restrict__ outb16)
{
    const int bx = blockIdx.x;
    const int cx = bx & 7, rr = bx >> 3;        // cx = XCD (dispatch round-robin)
    const int my = cx * 16 + (rr & 15);         // 16 m-panels per XCD
    const int mx = rr >> 4;                     // 8 n-panels, same XCD for fixed my

    const int tid  = threadIdx.x;
    const int wv   = tid >> 6;
    const int lane = tid & 63;
    const int wm = wv >> 1, wn = wv & 1;
    const int m0 = my * 64 + wm * 32;
    const int n0 = mx * 64 + wn * 32;
    const int lm = lane & 15, quad = lane >> 4;

    const ushort_t* ax  = xb16 + (size_t)(m0 + lm) * DP + quad * 8;
    const int ntg0 = mx * 4 + wn * 2;
    const ushort_t* bw0 = Wb16F + (size_t)(ntg0 * 15) * 512 + lane * 8;
    const ushort_t* bw1 = bw0 + 15 * 512;

    f32x4 acc[2][2];
#pragma unroll
    for (int i = 0; i < 2; ++i)
#pragma unroll
        for (int j = 0; j < 2; ++j) acc[i][j] = (f32x4){0.f, 0.f, 0.f, 0.f};

#pragma unroll 3
    for (int ks = 0; ks < 15; ++ks) {
        bf16x8 a0 = *(const bf16x8*)(ax + ks * 32);
        bf16x8 a1 = *(const bf16x8*)(ax + (size_t)16 * DP + ks * 32);
        bf16x8 b0 = *(const bf16x8*)(bw0 + ks * 512);
        bf16x8 b1 = *(const bf16x8*)(bw1 + ks * 512);
        acc[0][0] = MFMA16(a0, b0, acc[0][0], 0, 0, 0);
        acc[0][1] = MFMA16(a0, b1, acc[0][1], 0, 0, 0);
        acc[1][0] = MFMA16(a1, b0, acc[1][0], 0, 0, 0);
        acc[1][1] = MFMA16(a1, b1, acc[1][1], 0, 0, 0);
    }

#pragma unroll
    for (int nt = 0; nt < 2; ++nt) {
        const int n = n0 + nt * 16 + lm;
        const bool nval = (n < D);
        const float bv = nval ? bvec[n] : 0.f;
#pragma unroll
        for (int mt = 0; mt < 2; ++mt) {
#pragma unroll
            for (int r = 0; r < 4; ++r) {
                const int m = m0 + mt * 16 + quad * 4 + r;
                float y = acc[mt][nt][r] + bv;
                float g = 1.f / (1.f + __expf(-y));
                float o = 0.f;
                if (nval) {
                    float xo = xf32[(size_t)m * D + n];
                    o = g * fmaxf(y, 0.f) + (1.f - g) * xo;
                    out[(size_t)m * D + n] = o;
                }
                if (n < DP)
                    outb16[(size_t)m * DP + n] = f2b(nval ? o : 0.f);
            }
        }
    }
}

// ---------------- kernel 3a: attention prep -> fragment-major xF / xw3F / xTF ----------------
#define PXS 496   // LDS row stride (bf16)

__global__ __launch_bounds__(256) void attn_prep_kernel(
    const float* __restrict__ xf32, const float* __restrict__ attn_w, int layer,
    ushort_t* __restrict__ xF, ushort_t* __restrict__ xw3F, ushort_t* __restrict__ xTF,
    float* __restrict__ s1g, float* __restrict__ s2g)
{
    __shared__ ushort_t Xs[16 * PXS];     // 15872 B
    __shared__ ushort_t Xw3s[16 * PXS];   // 15872 B

    // XCD-affine siblings of one bh
    const int bx  = blockIdx.x;
    const int wid = (bx & 7) * 64 + (bx >> 3);
    const int bh  = wid >> 2, jq = wid & 3;
    const int tid = threadIdx.x;
    const int wv  = tid >> 6;
    const int lane = tid & 63;
    const size_t tok0 = (size_t)bh * 64 + jq * 16;

    const float* wb = attn_w + (size_t)layer * 3 * D;   // w1 | w2 | w3
    const float* w3 = wb + 2 * D;

    // ---- stage f2b(x) and f2b(x*w3) rows into LDS ----
#pragma unroll 1
    for (int c = tid; c < 16 * 60; c += 256) {
        const int j  = c / 60, k8 = c - j * 60;
        const int k0 = k8 * 8;
        const float* xr = xf32 + (tok0 + j) * D;
        bf16x8 xv, pv;
#pragma unroll
        for (int t = 0; t < 8; ++t) {
            const int k = k0 + t;
            const float x = (k < D) ? xr[k] : 0.f;
            xv[t] = (short)f2b(x);
            pv[t] = (short)f2b((k < D) ? x * w3[k] : 0.f);
        }
        *(bf16x8*)&Xs[j * PXS + k0]   = xv;
        *(bf16x8*)&Xw3s[j * PXS + k0] = pv;
    }

    // ---- s1/s2 dots: 4 rows per wave ----
#pragma unroll 1
    for (int rr = 0; rr < 4; ++rr) {
        const int j = wv * 4 + rr;
        const float* xr = xf32 + (tok0 + j) * D;
        float a1 = 0.f, a2 = 0.f;
#pragma unroll
        for (int t = 0; t < 8; ++t) {
            const int k = lane + t * 64;
            if (k < D) {
                float xv = xr[k];
                a1 = fmaf(xv, wb[k], a1);
                a2 = fmaf(xv, wb[D + k], a2);
            }
        }
        a1 = wave_sum(a1);
        a2 = wave_sum(a2);
        if (lane == 0) { s1g[tok0 + j] = a1; s2g[tok0 + j] = a2; }
    }
    __syncthreads();

    // ---- emit QK fragments (tile jt = jq), fully coalesced 16B ops ----
#pragma unroll 1
    for (int c = tid; c < 960; c += 256) {
        const int ks = c >> 6, l = c & 63;
        const int lnp = l & 15, qp = l >> 4;
        bf16x8 v = *(const bf16x8*)&Xs[lnp * PXS + ks * 32 + qp * 8];
        bf16x8 w = *(const bf16x8*)&Xw3s[lnp * PXS + ks * 32 + qp * 8];
        const size_t o = (size_t)bh * XFRAG + ((jq * 15 + ks) * 64 + l) * 8;
        *(bf16x8*)&xF[o]   = v;
        *(bf16x8*)&xw3F[o] = w;
    }

    // ---- emit AV B-fragments (transpose): this block owns 2 quads of each (dt, half) ----
    {
        const int half = jq >> 1, q0 = (jq & 1) * 2;
#pragma unroll 1
        for (int c = tid; c < 960; c += 256) {
            const int dt = c >> 5, s = c & 31;
            const int qp = q0 + (s >> 4), lnp = s & 15;
            const int d  = dt * 16 + lnp;
            const int jb = (qp & 1) * 8;
            bf16x8 v;
#pragma unroll
            for (int e = 0; e < 8; ++e) v[e] = (short)Xs[(jb + e) * PXS + d];
            *(bf16x8*)&xTF[(size_t)bh * XFRAG + ((dt * 2 + half) * 64 + qp * 16 + lnp) * 8] = v;
        }
    }
}

// ---------------- kernel 3b: attention core (all fragment loads coalesced) ----------------
#define ALS 72    // P LDS row stride (bf16)

template <bool RES_EMIT>
__global__ __launch_bounds__(256) void attn_fused_kernel(
    const float* __restrict__ xf32,
    const ushort_t* __restrict__ xF, const ushort_t* __restrict__ xw3F,
    const ushort_t* __restrict__ xTF,
    const float* __restrict__ s1g, const float* __restrict__ s2g,
    const int* __restrict__ q1_len, const int* __restrict__ q2_len,
    const float* __restrict__ attn_b, int layer,
    float* __restrict__ outf)
{
    __shared__ float    sc[16][68];   // masked scores, 4352 B
    __shared__ ushort_t Al[16 * ALS]; // P (bf16), 2304 B

    // XCD swizzle: 4 sibling blocks of one bh share an XCD's L2.
    const int bx  = blockIdx.x;
    const int wid = (bx & 7) * 64 + (bx >> 3);
    const int bh  = wid >> 2, iq = wid & 3;
    const int branch = bh >> 6, b = bh & 63;
    const int tid  = threadIdx.x;
    const int wv   = tid >> 6;
    const int lane = tid & 63;
    const int ln   = lane & 15, quad = lane >> 4;
    const int i0   = iq * 16;

    // ---- QK^T: wave wv computes scores[16 i][16 j] for j-tile wv ----
    const ushort_t* xa = xF   + (size_t)bh * XFRAG + (iq * 15 * 64 + lane) * 8;
    const ushort_t* xb = xw3F + (size_t)bh * XFRAG + (wv * 15 * 64 + lane) * 8;

    f32x4 qa0 = (f32x4){0.f, 0.f, 0.f, 0.f};
    f32x4 qa1 = (f32x4){0.f, 0.f, 0.f, 0.f};
#pragma unroll
    for (int ks = 0; ks < 14; ks += 2) {
        bf16x8 a0 = *(const bf16x8*)(xa + ks * 512);
        bf16x8 b0 = *(const bf16x8*)(xb + ks * 512);
        bf16x8 a1 = *(const bf16x8*)(xa + ks * 512 + 512);
        bf16x8 b1 = *(const bf16x8*)(xb + ks * 512 + 512);
        qa0 = MFMA16(a0, b0, qa0, 0, 0, 0);
        qa1 = MFMA16(a1, b1, qa1, 0, 0, 0);
    }
    {
        bf16x8 a  = *(const bf16x8*)(xa + 14 * 512);
        bf16x8 bq = *(const bf16x8*)(xb + 14 * 512);
        qa0 = MFMA16(a, bq, qa0, 0, 0, 0);
    }
    f32x4 qacc = qa0 + qa1;

    const int   len  = (branch ? q2_len : q1_len)[b];
    const float bias = attn_b[layer];
    const int   j    = wv * 16 + ln;
    const float s2v  = s2g[bh * 64 + j];
#pragma unroll
    for (int reg = 0; reg < 4; ++reg) {
        const int i = i0 + quad * 4 + reg;
        float v = qacc[reg] + s1g[bh * 64 + i] + s2v + bias;
        if (j >= len) v = -1e-9f;        // reference's (buggy) mask value
        sc[quad * 4 + reg][j] = v;
    }
    __syncthreads();

    // ---- softmax: wave wv handles local rows wv*4..wv*4+3, full 64-lane row ----
#pragma unroll
    for (int rr = 0; rr < 4; ++rr) {
        const int r = wv * 4 + rr;
        float v = sc[r][lane];
        float m = v;
#pragma unroll
        for (int o = 32; o; o >>= 1) m = fmaxf(m, __shfl_xor(m, o, 64));
        float ev = __expf(v - m);
        float sm = ev;
#pragma unroll
        for (int o = 32; o; o >>= 1) sm += __shfl_xor(sm, o, 64);
        Al[r * ALS + lane] = f2b(ev * (1.f / sm));
    }
    __syncthreads();

    // ---- AV: out[i][d] = sum_j P[i][j] X[j][d]; d-tiles round-robin over waves ----
    const ushort_t* xTb = xTF + (size_t)bh * XFRAG + lane * 8;
    bf16x8 af0 = *(const bf16x8*)&Al[ln * ALS + quad * 8];
    bf16x8 af1 = *(const bf16x8*)&Al[ln * ALS + quad * 8 + 32];

#pragma unroll 2
    for (int dt = wv; dt < 30; dt += 4) {
        bf16x8 b0 = *(const bf16x8*)(xTb + dt * 1024);
        bf16x8 b1 = *(const bf16x8*)(xTb + dt * 1024 + 512);
        f32x4 acc = (f32x4){0.f, 0.f, 0.f, 0.f};
        acc = MFMA16(af0, b0, acc, 0, 0, 0);
        acc = MFMA16(af1, b1, acc, 0, 0, 0);

        const int d = dt * 16 + ln;
        if (d < D) {
#pragma unroll
            for (int reg = 0; reg < 4; ++reg) {
                const int i = i0 + quad * 4 + reg;
                float v = acc[reg];
                if (RES_EMIT) v += xf32[((size_t)bh * 64 + i) * D + d];
                outf[((size_t)bh * 64 + i) * D + d] = v;
            }
        }
    }
}

// ---------------- launch ----------------
extern "C" void kernel_launch(void* const* d_in, const int* in_sizes, int n_in,
                              void* d_out, int out_size, void* d_ws, size_t ws_size,
                              hipStream_t stream) {
    const int*   q1       = (const int*)  d_in[0];
    const int*   q2       = (const int*)  d_in[1];
    const int*   q1_len   = (const int*)  d_in[2];
    const int*   q2_len   = (const int*)  d_in[3];
    const int*   q1c      = (const int*)  d_in[4];
    const int*   q2c      = (const int*)  d_in[5];
    const float* word_emb = (const float*)d_in[6];
    const float* char_emb = (const float*)d_in[7];
    const float* w3       = (const float*)d_in[8];
    const float* b3       = (const float*)d_in[9];
    const float* w4       = (const float*)d_in[10];
    const float* b4       = (const float*)d_in[11];
    const float* w5       = (const float*)d_in[12];
    const float* b5       = (const float*)d_in[13];
    const float* hw_w     = (const float*)d_in[14];
    const float* hw_b     = (const float*)d_in[15];
    const float* attn_w   = (const float*)d_in[16];
    const float* attn_b   = (const float*)d_in[17];
    float* out = (float*)d_out;

    float*    buf0    = (float*)d_ws;                          // 2*NT*D f32
    float*    buf1    = buf0 + (size_t)2 * NT * D;             // 2*NT*D f32
    float*    bias160 = buf1 + (size_t)2 * NT * D;             // 160 f32
    ushort_t* xb16a   = (ushort_t*)(bias160 + 160);            // 2*NT*DP bf16
    ushort_t* xb16b   = xb16a + (size_t)2 * NT * DP;           // 2*NT*DP bf16
    ushort_t* Wb16F   = xb16b + (size_t)2 * NT * DP;           // WBF_N bf16
    ushort_t* WpadF   = Wb16F + (size_t)WBF_N;                 // WPF_N bf16
    ushort_t* ceb16   = WpadF + (size_t)WPF_N;                 // 100*64 bf16
    ushort_t* xF      = ceb16 + (size_t)100 * 64;              // 128*XFRAG bf16
    ushort_t* xw3F    = xF   + (size_t)NBH * XFRAG;            // 128*XFRAG bf16
    ushort_t* xTF     = xw3F + (size_t)NBH * XFRAG;            // 128*XFRAG bf16
    float*    s1g     = (float*)(xTF + (size_t)NBH * XFRAG);   // 2*NT f32
    float*    s2g     = s1g + (size_t)2 * NT;                  // 2*NT f32

    // 1. fragment-major weight prep + fused embed/conv
    prep_kernel<<<(WBF_N + WPF_N + 160 + 100 * 64 + 255) / 256, 256, 0, stream>>>(
        hw_w, w3, b3, w4, b4, w5, b5, char_emb, Wb16F, WpadF, bias160, ceb16);
    embed_conv_kernel<<<1024, 256, 0, stream>>>(q1, q2, q1c, q2c, word_emb, ceb16,
                                                WpadF, bias160, buf0, xb16a);

    // 2. highway x2 via MFMA (XCD-affine, coalesced B)
    highway_mfma_kernel<<<1024, 256, 0, stream>>>(xb16a, buf0, Wb16F, hw_b, buf1, xb16b);
    highway_mfma_kernel<<<1024, 256, 0, stream>>>(xb16b, buf1, Wb16F, hw_b, buf0, xb16a);

    // 3. attn layer 0: prep (fragment-major) from buf0, core -> buf1 (residual fused)
    attn_prep_kernel<<<512, 256, 0, stream>>>(buf0, attn_w, 0, xF, xw3F, xTF, s1g, s2g);
    attn_fused_kernel<true><<<512, 256, 0, stream>>>(
        buf0, xF, xw3F, xTF, s1g, s2g, q1_len, q2_len, attn_b, 0, buf1);

    // 4. attn layer 1: prep from buf1, core -> d_out
    attn_prep_kernel<<<512, 256, 0, stream>>>(buf1, attn_w, 1, xF, xw3F, xTF, s1g, s2g);
    attn_fused_kernel<false><<<512, 256, 0, stream>>>(
        buf1, xF, xw3F, xTF, s1g, s2g, q1_len, q2_len, attn_b, 1, out);
}

// Round 6
// 323.348 us; speedup vs baseline: 1.2513x; 1.0508x over previous
//
#include <hip/hip_runtime.h>
#include <math.h>

// ---- problem constants ----
#define B   64
#define L   64
#define C   16
#define CHD 64
#define EMB 300
#define D   450       // EMB + 3*50
#define DP  480       // padded bf16 dim count
#define NT  (B*L)     // 4096 tokens per branch
#define NBH 128       // 2 branches * 64 batch

typedef short bf16x8 __attribute__((ext_vector_type(8)));
typedef float f32x4  __attribute__((ext_vector_type(4)));
typedef float f32x2  __attribute__((ext_vector_type(2)));
typedef unsigned short ushort_t;
typedef ushort_t us4 __attribute__((ext_vector_type(4)));

#define MFMA16 __builtin_amdgcn_mfma_f32_16x16x32_bf16

// fragment-major sizes
#define WPF_N (10 * 10 * 512)           // WpadF: 10 nt x 10 ks x 64 lane x 8
#define WBF_N (32 * 15 * 512)           // Wb16F: 32 nt x 15 ks x 64 lane x 8
#define XFRAG 30720                     // per-bh: 4 tiles x 15 ks x 512 (= 64 tok x 480)

// ---------------- helpers ----------------
__device__ inline float wave_sum(float v) {
#pragma unroll
    for (int o = 32; o; o >>= 1) v += __shfl_xor(v, o, 64);
    return v;
}
__device__ inline ushort_t f2b(float f) {   // RNE float->bf16
    union { float f; unsigned u; } c; c.f = f;
    unsigned r = c.u + 0x7FFFu + ((c.u >> 16) & 1u);
    return (ushort_t)(r >> 16);
}

// ---------------- kernel P: fused weight prep (fragment-major images) ----------------
__global__ __launch_bounds__(256) void prep_kernel(
    const float* __restrict__ W,
    const float* __restrict__ w3, const float* __restrict__ b3,
    const float* __restrict__ w4, const float* __restrict__ b4,
    const float* __restrict__ w5, const float* __restrict__ b5,
    const float* __restrict__ char_emb,
    ushort_t* __restrict__ Wb16F, ushort_t* __restrict__ WpadF,
    float* __restrict__ bias160, ushort_t* __restrict__ ceb16)
{
    int idx = blockIdx.x * 256 + threadIdx.x;
    if (idx < WBF_N) {   // highway weight fragments
        const int e = idx & 7, l = (idx >> 3) & 63, t = idx >> 9;
        const int ks = t % 15, nt = t / 15;
        const int ln = l & 15, q = l >> 4;
        const int n = nt * 16 + ln, k = ks * 32 + q * 8 + e;
        float v = (n < D && k < D) ? W[(size_t)n * D + k] : 0.f;
        Wb16F[idx] = f2b(v);
        return;
    }
    idx -= WBF_N;
    if (idx < WPF_N) {   // conv weight fragments
        const int e = idx & 7, l = (idx >> 3) & 63, t = idx >> 9;
        const int ks = t % 10, nt = t / 10;
        const int ln = l & 15, q = l >> 4;
        const int f = nt * 16 + ln;
        const int kd = ks * 32 + q * 8 + e;
        const int k = kd >> 6, d = kd & 63;
        float v = 0.f;
        if (f < 50)       { if (k < 3) v = w3[f * 192 + d * 3 + k]; }
        else if (f < 100) { if (k < 4) v = w4[(f - 50) * 256 + d * 4 + k]; }
        else if (f < 150) { v = w5[(f - 100) * 320 + d * 5 + k]; }
        WpadF[idx] = f2b(v);
        return;
    }
    idx -= WPF_N;
    if (idx < 160) {
        bias160[idx] = (idx < 50) ? b3[idx] : (idx < 100) ? b4[idx - 50]
                     : (idx < 150) ? b5[idx - 100] : 0.f;
    } else if (idx < 160 + 100 * 64) {
        int i = idx - 160;
        ceb16[i] = f2b(char_emb[i]);
    }
}

// ---------------- kernel 1: fused word-embed copy + char conv -> f32 rows + xbF ----------------
#define ESS 72
#define EST (20 * ESS)
#define XTS1 488   // per-token bf16 staging stride

__global__ __launch_bounds__(256) void embed_conv_kernel(
    const int* __restrict__ q1, const int* __restrict__ q2,
    const int* __restrict__ q1c, const int* __restrict__ q2c,
    const float* __restrict__ word_emb, const ushort_t* __restrict__ ceb16,
    const ushort_t* __restrict__ WpadF, const float* __restrict__ bias160,
    float* __restrict__ xout, ushort_t* __restrict__ xbF)
{
    __shared__ ushort_t es[8 * EST];     // 23040 B (f32 smf overlay in epilogue)
    __shared__ ushort_t Xt[8 * XTS1];    // 7808 B bf16 row staging

    const int tid  = threadIdx.x;
    const int wv   = tid >> 6;
    const int lane = tid & 63;
    const int ln   = lane & 15, quad = lane >> 4;
    const int bx   = blockIdx.x;
    const int tokbase = ((bx & 7) * 128 + (bx >> 3)) * 8;   // XCD-affine

    // ---- stage char-embedding rows for 8 tokens ----
#pragma unroll
    for (int i = 0; i < 4; ++i) {
        int c = tid + i * 256;
        int row = c >> 3, part = c & 7;
        int tl = row >> 4, cr = row & 15;
        int gtok   = tokbase + tl;
        int branch = gtok >> 12;
        int tokl   = gtok & (NT - 1);
        int cid    = (branch ? q2c : q1c)[tokl * C + cr];
        *(bf16x8*)&es[tl * EST + cr * ESS + part * 8] =
            *(const bf16x8*)&ceb16[cid * 64 + part * 8];
    }
    {   // zero the 4 pad rows per token
        int tl = tid >> 5, rr = (tid >> 3) & 3, part = tid & 7;
        bf16x8 z = {0, 0, 0, 0, 0, 0, 0, 0};
        *(bf16x8*)&es[tl * EST + (16 + rr) * ESS + part * 8] = z;
    }

    // ---- word-embedding copy (f32 global + bf16 LDS staging) ----
#pragma unroll 1
    for (int c = tid; c < 8 * 75; c += 256) {
        const int t  = c / 75, d4 = c - t * 75;
        const int tok    = tokbase + t;
        const int branch = tok >> 12;
        const int tokl   = tok & (NT - 1);
        const int w      = (branch ? q2 : q1)[tokl];
        const float4 v = *(const float4*)(word_emb + (size_t)w * EMB + d4 * 4);
        float* dst = xout + (size_t)tok * D + d4 * 4;
        *(f32x2*)dst       = (f32x2){v.x, v.y};
        *(f32x2*)(dst + 2) = (f32x2){v.z, v.w};
        us4 pk = { f2b(v.x), f2b(v.y), f2b(v.z), f2b(v.w) };
        *(us4*)&Xt[t * XTS1 + d4 * 4] = pk;
    }
    if (tid < 240) {   // zero bf16 pad cols 450..479
        const int t = tid / 30, k = tid - t * 30;
        Xt[t * XTS1 + D + k] = 0;
    }
    __syncthreads();

    // ---- conv via MFMA (A from LDS, B coalesced from WpadF) ----
    const int t0 = wv * 2, t1 = t0 + 1;
    f32x4 acc[2][10];
#pragma unroll
    for (int t = 0; t < 2; ++t)
#pragma unroll
        for (int nt = 0; nt < 10; ++nt) acc[t][nt] = (f32x4){0.f, 0.f, 0.f, 0.f};

#pragma unroll 1
    for (int ks = 0; ks < 10; ++ks) {
        const int kk   = ks * 32 + quad * 8;
        const int arow = kk >> 6, aoff = kk & 63;
        bf16x8 a0 = *(const bf16x8*)&es[t0 * EST + (ln + arow) * ESS + aoff];
        bf16x8 a1 = *(const bf16x8*)&es[t1 * EST + (ln + arow) * ESS + aoff];
#pragma unroll
        for (int nt = 0; nt < 10; ++nt) {
            bf16x8 bf = *(const bf16x8*)&WpadF[(size_t)((nt * 10 + ks) << 9) + lane * 8];
            acc[0][nt] = MFMA16(a0, bf, acc[0][nt], 0, 0, 0);
            acc[1][nt] = MFMA16(a1, bf, acc[1][nt], 0, 0, 0);
        }
    }
    __syncthreads();   // es reads done; reuse as f32 staging

    // ---- epilogue: reduce -> LDS, coalesced f32 emit + bf16 staging ----
    float* smf = (float*)es;   // [8][160] f32
#pragma unroll
    for (int t = 0; t < 2; ++t) {
        const int tloc = t0 + t;
#pragma unroll
        for (int nt = 0; nt < 10; ++nt) {
            const int f  = nt * 16 + ln;
            const int Pf = (f < 50) ? 14 : (f < 100) ? 13 : 12;
            float m = -1e30f;
#pragma unroll
            for (int r = 0; r < 4; ++r) {
                const int p = quad * 4 + r;
                if (p < Pf) m = fmaxf(m, acc[t][nt][r]);
            }
            m = fmaxf(m, __shfl_xor(m, 16, 64));
            m = fmaxf(m, __shfl_xor(m, 32, 64));
            if (quad == 0) smf[tloc * 160 + f] = fmaxf(0.f, m + bias160[f]);
        }
    }
    __syncthreads();
#pragma unroll 1
    for (int c = tid; c < 8 * 150; c += 256) {
        const int t = c / 150, f = c - t * 150;
        const float rv = smf[t * 160 + f];
        xout[(size_t)(tokbase + t) * D + EMB + f] = rv;
        Xt[t * XTS1 + EMB + f] = f2b(rv);
    }
    __syncthreads();

    // ---- fragment-major emit: this block owns half (8 of 16 lanes) of tile tokbase>>4 ----
    {
        const int tile = tokbase >> 4, half = (tokbase >> 3) & 1;
#pragma unroll 1
        for (int c = tid; c < 480; c += 256) {
            const int ksl = c >> 5, s = c & 31;
            const int q = s >> 3, tl = s & 7;
            const int l = q * 16 + half * 8 + tl;
            bf16x8 v = *(const bf16x8*)&Xt[tl * XTS1 + ksl * 32 + q * 8];
            *(bf16x8*)&xbF[((size_t)(tile * 15 + ksl) * 64 + l) * 8] = v;
        }
    }
}

// ---------------- kernel 2: highway, fully fragment-major operands ----------------
#define HLS 72   // 64x64 re-tile LDS stride

__global__ __launch_bounds__(256, 4) void highway_mfma_kernel(
    const ushort_t* __restrict__ xbFi, const float* __restrict__ xf32,
    const ushort_t* __restrict__ Wb16F, const float* __restrict__ bvec,
    float* __restrict__ out, ushort_t* __restrict__ xbFo)
{
    __shared__ ushort_t Xl[64 * HLS];   // 9216 B

    const int bx = blockIdx.x;
    const int cx = bx & 7, rr = bx >> 3;        // cx = XCD
    const int my = cx * 16 + (rr & 15);         // token panel (64 tokens)
    const int mx = rr >> 4;                     // n panel (64 dims)

    const int tid  = threadIdx.x;
    const int wv   = tid >> 6;
    const int lane = tid & 63;
    const int wm = wv >> 1, wn = wv & 1;
    const int m0 = my * 64 + wm * 32;
    const int n0 = mx * 64 + wn * 32;
    const int lm = lane & 15, quad = lane >> 4;

    const int tA0 = my * 4 + wm * 2;
    const ushort_t* ax0 = xbFi + (size_t)(tA0 * 15) * 512 + lane * 8;
    const ushort_t* ax1 = ax0 + 15 * 512;
    const int ntg0 = mx * 4 + wn * 2;
    const ushort_t* bw0 = Wb16F + (size_t)(ntg0 * 15) * 512 + lane * 8;
    const ushort_t* bw1 = bw0 + 15 * 512;

    f32x4 acc[2][2];
#pragma unroll
    for (int i = 0; i < 2; ++i)
#pragma unroll
        for (int j = 0; j < 2; ++j) acc[i][j] = (f32x4){0.f, 0.f, 0.f, 0.f};

#pragma unroll 3
    for (int ks = 0; ks < 15; ++ks) {
        bf16x8 a0 = *(const bf16x8*)(ax0 + ks * 512);
        bf16x8 a1 = *(const bf16x8*)(ax1 + ks * 512);
        bf16x8 b0 = *(const bf16x8*)(bw0 + ks * 512);
        bf16x8 b1 = *(const bf16x8*)(bw1 + ks * 512);
        acc[0][0] = MFMA16(a0, b0, acc[0][0], 0, 0, 0);
        acc[0][1] = MFMA16(a0, b1, acc[0][1], 0, 0, 0);
        acc[1][0] = MFMA16(a1, b0, acc[1][0], 0, 0, 0);
        acc[1][1] = MFMA16(a1, b1, acc[1][1], 0, 0, 0);
    }

#pragma unroll
    for (int nt = 0; nt < 2; ++nt) {
        const int n  = n0 + nt * 16 + lm;
        const int nl = wn * 32 + nt * 16 + lm;
        const bool nval = (n < D);
        const float bv = nval ? bvec[n] : 0.f;
#pragma unroll
        for (int mt = 0; mt < 2; ++mt) {
#pragma unroll
            for (int r = 0; r < 4; ++r) {
                const int m  = m0 + mt * 16 + quad * 4 + r;
                const int ml = wm * 32 + mt * 16 + quad * 4 + r;
                float y = acc[mt][nt][r] + bv;
                float g = 1.f / (1.f + __expf(-y));
                float o = 0.f;
                if (nval) {
                    float xo = xf32[(size_t)m * D + n];
                    o = g * fmaxf(y, 0.f) + (1.f - g) * xo;
                    out[(size_t)m * D + n] = o;
                }
                Xl[ml * HLS + nl] = f2b(nval ? o : 0.f);
            }
        }
    }
    __syncthreads();

    // ---- fragment-major emit: 4 token tiles x 2 ks slots ----
#pragma unroll 1
    for (int c = tid; c < 512; c += 256) {
        const int fi = c >> 6, l = c & 63;
        const int tl = fi >> 1, ksl = fi & 1;
        const int ksg = mx * 2 + ksl;
        if (ksg < 15) {
            const int lnp = l & 15, qp = l >> 4;
            bf16x8 v = *(const bf16x8*)&Xl[(tl * 16 + lnp) * HLS + ksl * 32 + qp * 8];
            *(bf16x8*)&xbFo[((size_t)((my * 4 + tl) * 15 + ksg) * 64 + l) * 8] = v;
        }
    }
}

// ---------------- kernel 3a: attention prep -> xw3F / xTF / s1 / s2 ----------------
#define PXS 496   // LDS row stride (bf16)

__global__ __launch_bounds__(256) void attn_prep_kernel(
    const float* __restrict__ xf32, const float* __restrict__ attn_w, int layer,
    ushort_t* __restrict__ xw3F, ushort_t* __restrict__ xTF,
    float* __restrict__ s1g, float* __restrict__ s2g)
{
    __shared__ ushort_t Xs[16 * PXS];     // 15872 B
    __shared__ ushort_t Xw3s[16 * PXS];   // 15872 B

    const int bx  = blockIdx.x;
    const int wid = (bx & 7) * 64 + (bx >> 3);
    const int bh  = wid >> 2, jq = wid & 3;
    const int tid = threadIdx.x;
    const int wv  = tid >> 6;
    const int lane = tid & 63;
    const size_t tok0 = (size_t)bh * 64 + jq * 16;

    const float* wb = attn_w + (size_t)layer * 3 * D;   // w1 | w2 | w3
    const float* w3 = wb + 2 * D;

    // ---- stage f2b(x) and f2b(x*w3) rows into LDS ----
#pragma unroll 1
    for (int c = tid; c < 16 * 60; c += 256) {
        const int j  = c / 60, k8 = c - j * 60;
        const int k0 = k8 * 8;
        const float* xr = xf32 + (tok0 + j) * D;
        bf16x8 xv, pv;
#pragma unroll
        for (int t = 0; t < 8; ++t) {
            const int k = k0 + t;
            const float x = (k < D) ? xr[k] : 0.f;
            xv[t] = (short)f2b(x);
            pv[t] = (short)f2b((k < D) ? x * w3[k] : 0.f);
        }
        *(bf16x8*)&Xs[j * PXS + k0]   = xv;
        *(bf16x8*)&Xw3s[j * PXS + k0] = pv;
    }

    // ---- s1/s2 dots: 4 rows per wave ----
#pragma unroll 1
    for (int rr = 0; rr < 4; ++rr) {
        const int j = wv * 4 + rr;
        const float* xr = xf32 + (tok0 + j) * D;
        float a1 = 0.f, a2 = 0.f;
#pragma unroll
        for (int t = 0; t < 8; ++t) {
            const int k = lane + t * 64;
            if (k < D) {
                float xv = xr[k];
                a1 = fmaf(xv, wb[k], a1);
                a2 = fmaf(xv, wb[D + k], a2);
            }
        }
        a1 = wave_sum(a1);
        a2 = wave_sum(a2);
        if (lane == 0) { s1g[tok0 + j] = a1; s2g[tok0 + j] = a2; }
    }
    __syncthreads();

    // ---- emit xw3 QK fragments (tile jq), coalesced ----
#pragma unroll 1
    for (int c = tid; c < 960; c += 256) {
        const int ks = c >> 6, l = c & 63;
        const int lnp = l & 15, qp = l >> 4;
        bf16x8 w = *(const bf16x8*)&Xw3s[lnp * PXS + ks * 32 + qp * 8];
        *(bf16x8*)&xw3F[(size_t)bh * XFRAG + ((jq * 15 + ks) * 64 + l) * 8] = w;
    }

    // ---- emit AV B-fragments (transpose) ----
    {
        const int half = jq >> 1, q0 = (jq & 1) * 2;
#pragma unroll 1
        for (int c = tid; c < 960; c += 256) {
            const int dt = c >> 5, s = c & 31;
            const int qp = q0 + (s >> 4), lnp = s & 15;
            const int d  = dt * 16 + lnp;
            const int jb = (qp & 1) * 8;
            bf16x8 v;
#pragma unroll
            for (int e = 0; e < 8; ++e) v[e] = (short)Xs[(jb + e) * PXS + d];
            *(bf16x8*)&xTF[(size_t)bh * XFRAG + ((dt * 2 + half) * 64 + qp * 16 + lnp) * 8] = v;
        }
    }
}

// ---------------- kernel 3b: attention core ----------------
#define ALS 72    // P LDS row stride (bf16)

template <bool RES_EMIT>
__global__ __launch_bounds__(256) void attn_fused_kernel(
    const float* __restrict__ xf32,
    const ushort_t* __restrict__ xF, const ushort_t* __restrict__ xw3F,
    const ushort_t* __restrict__ xTF,
    const float* __restrict__ s1g, const float* __restrict__ s2g,
    const int* __restrict__ q1_len, const int* __restrict__ q2_len,
    const float* __restrict__ attn_b, int layer,
    float* __restrict__ outf, ushort_t* __restrict__ xbFo)
{
    __shared__ float    sc[16][68];   // masked scores, 4352 B
    __shared__ ushort_t Al[16 * ALS]; // P (bf16), 2304 B
    __shared__ ushort_t At[RES_EMIT ? 16 * XTS1 : 8];   // bf16 out staging

    const int bx  = blockIdx.x;
    const int wid = (bx & 7) * 64 + (bx >> 3);
    const int bh  = wid >> 2, iq = wid & 3;
    const int branch = bh >> 6, b = bh & 63;
    const int tid  = threadIdx.x;
    const int wv   = tid >> 6;
    const int lane = tid & 63;
    const int ln   = lane & 15, quad = lane >> 4;
    const int i0   = iq * 16;

    if (RES_EMIT) {   // zero bf16 pad cols 450..479 (16 tokens x 30)
        for (int c = tid; c < 480; c += 256) {
            const int t = c / 30, k = c - t * 30;
            At[t * XTS1 + D + k] = 0;
        }
    }

    // ---- QK^T: wave wv computes scores[16 i][16 j] for j-tile wv ----
    const ushort_t* xa = xF   + (size_t)bh * XFRAG + (iq * 15 * 64 + lane) * 8;
    const ushort_t* xb = xw3F + (size_t)bh * XFRAG + (wv * 15 * 64 + lane) * 8;

    f32x4 qa0 = (f32x4){0.f, 0.f, 0.f, 0.f};
    f32x4 qa1 = (f32x4){0.f, 0.f, 0.f, 0.f};
#pragma unroll
    for (int ks = 0; ks < 14; ks += 2) {
        bf16x8 a0 = *(const bf16x8*)(xa + ks * 512);
        bf16x8 b0 = *(const bf16x8*)(xb + ks * 512);
        bf16x8 a1 = *(const bf16x8*)(xa + ks * 512 + 512);
        bf16x8 b1 = *(const bf16x8*)(xb + ks * 512 + 512);
        qa0 = MFMA16(a0, b0, qa0, 0, 0, 0);
        qa1 = MFMA16(a1, b1, qa1, 0, 0, 0);
    }
    {
        bf16x8 a  = *(const bf16x8*)(xa + 14 * 512);
        bf16x8 bq = *(const bf16x8*)(xb + 14 * 512);
        qa0 = MFMA16(a, bq, qa0, 0, 0, 0);
    }
    f32x4 qacc = qa0 + qa1;

    const int   len  = (branch ? q2_len : q1_len)[b];
    const float bias = attn_b[layer];
    const int   j    = wv * 16 + ln;
    const float s2v  = s2g[bh * 64 + j];
#pragma unroll
    for (int reg = 0; reg < 4; ++reg) {
        const int i = i0 + quad * 4 + reg;
        float v = qacc[reg] + s1g[bh * 64 + i] + s2v + bias;
        if (j >= len) v = -1e-9f;        // reference's (buggy) mask value
        sc[quad * 4 + reg][j] = v;
    }
    __syncthreads();

    // ---- softmax ----
#pragma unroll
    for (int rr = 0; rr < 4; ++rr) {
        const int r = wv * 4 + rr;
        float v = sc[r][lane];
        float m = v;
#pragma unroll
        for (int o = 32; o; o >>= 1) m = fmaxf(m, __shfl_xor(m, o, 64));
        float ev = __expf(v - m);
        float sm = ev;
#pragma unroll
        for (int o = 32; o; o >>= 1) sm += __shfl_xor(sm, o, 64);
        Al[r * ALS + lane] = f2b(ev * (1.f / sm));
    }
    __syncthreads();

    // ---- AV + epilogue ----
    const ushort_t* xTb = xTF + (size_t)bh * XFRAG + lane * 8;
    bf16x8 af0 = *(const bf16x8*)&Al[ln * ALS + quad * 8];
    bf16x8 af1 = *(const bf16x8*)&Al[ln * ALS + quad * 8 + 32];

#pragma unroll 2
    for (int dt = wv; dt < 30; dt += 4) {
        bf16x8 b0 = *(const bf16x8*)(xTb + dt * 1024);
        bf16x8 b1 = *(const bf16x8*)(xTb + dt * 1024 + 512);
        f32x4 acc = (f32x4){0.f, 0.f, 0.f, 0.f};
        acc = MFMA16(af0, b0, acc, 0, 0, 0);
        acc = MFMA16(af1, b1, acc, 0, 0, 0);

        const int d = dt * 16 + ln;
        if (d < D) {
#pragma unroll
            for (int reg = 0; reg < 4; ++reg) {
                const int i = i0 + quad * 4 + reg;
                float v = acc[reg];
                if (RES_EMIT) v += xf32[((size_t)bh * 64 + i) * D + d];
                outf[((size_t)bh * 64 + i) * D + d] = v;
                if (RES_EMIT)
                    At[(quad * 4 + reg) * XTS1 + d] = f2b(v);
            }
        }
    }

    if (RES_EMIT) {   // fragment-major emit of (att + x) as next layer's xF tile
        __syncthreads();
#pragma unroll 1
        for (int c = tid; c < 960; c += 256) {
            const int ksl = c >> 6, l = c & 63;
            const int lnp = l & 15, qp = l >> 4;
            bf16x8 v = *(const bf16x8*)&At[lnp * XTS1 + ksl * 32 + qp * 8];
            *(bf16x8*)&xbFo[((size_t)((bh * 4 + iq) * 15 + ksl) * 64 + l) * 8] = v;
        }
    }
}

// ---------------- launch ----------------
extern "C" void kernel_launch(void* const* d_in, const int* in_sizes, int n_in,
                              void* d_out, int out_size, void* d_ws, size_t ws_size,
                              hipStream_t stream) {
    const int*   q1       = (const int*)  d_in[0];
    const int*   q2       = (const int*)  d_in[1];
    const int*   q1_len   = (const int*)  d_in[2];
    const int*   q2_len   = (const int*)  d_in[3];
    const int*   q1c      = (const int*)  d_in[4];
    const int*   q2c      = (const int*)  d_in[5];
    const float* word_emb = (const float*)d_in[6];
    const float* char_emb = (const float*)d_in[7];
    const float* w3       = (const float*)d_in[8];
    const float* b3       = (const float*)d_in[9];
    const float* w4       = (const float*)d_in[10];
    const float* b4       = (const float*)d_in[11];
    const float* w5       = (const float*)d_in[12];
    const float* b5       = (const float*)d_in[13];
    const float* hw_w     = (const float*)d_in[14];
    const float* hw_b     = (const float*)d_in[15];
    const float* attn_w   = (const float*)d_in[16];
    const float* attn_b   = (const float*)d_in[17];
    float* out = (float*)d_out;

    float*    buf0    = (float*)d_ws;                          // 2*NT*D f32
    float*    buf1    = buf0 + (size_t)2 * NT * D;             // 2*NT*D f32
    float*    bias160 = buf1 + (size_t)2 * NT * D;             // 160 f32
    ushort_t* xbFa    = (ushort_t*)(bias160 + 160);            // 2*NT*DP bf16 (fragment-major)
    ushort_t* xbFb    = xbFa + (size_t)2 * NT * DP;            // 2*NT*DP bf16
    ushort_t* Wb16F   = xbFb + (size_t)2 * NT * DP;            // WBF_N bf16
    ushort_t* WpadF   = Wb16F + (size_t)WBF_N;                 // WPF_N bf16
    ushort_t* ceb16   = WpadF + (size_t)WPF_N;                 // 100*64 bf16
    ushort_t* xw3F    = ceb16 + (size_t)100 * 64;              // 128*XFRAG bf16
    ushort_t* xTF     = xw3F + (size_t)NBH * XFRAG;            // 128*XFRAG bf16
    float*    s1g     = (float*)(xTF + (size_t)NBH * XFRAG);   // 2*NT f32
    float*    s2g     = s1g + (size_t)2 * NT;                  // 2*NT f32

    // 1. fragment-major weight prep + fused embed/conv -> buf0 + xbFa
    prep_kernel<<<(WBF_N + WPF_N + 160 + 100 * 64 + 255) / 256, 256, 0, stream>>>(
        hw_w, w3, b3, w4, b4, w5, b5, char_emb, Wb16F, WpadF, bias160, ceb16);
    embed_conv_kernel<<<1024, 256, 0, stream>>>(q1, q2, q1c, q2c, word_emb, ceb16,
                                                WpadF, bias160, buf0, xbFa);

    // 2. highway x2 (all operands fragment-major)
    highway_mfma_kernel<<<1024, 256, 0, stream>>>(xbFa, buf0, Wb16F, hw_b, buf1, xbFb);
    highway_mfma_kernel<<<1024, 256, 0, stream>>>(xbFb, buf1, Wb16F, hw_b, buf0, xbFa);

    // 3. attn layer 0: prep from buf0; core reads xbFa, emits buf1 + xbFb
    attn_prep_kernel<<<512, 256, 0, stream>>>(buf0, attn_w, 0, xw3F, xTF, s1g, s2g);
    attn_fused_kernel<true><<<512, 256, 0, stream>>>(
        buf0, xbFa, xw3F, xTF, s1g, s2g, q1_len, q2_len, attn_b, 0, buf1, xbFb);

    // 4. attn layer 1: prep from buf1; core reads xbFb -> d_out
    attn_prep_kernel<<<512, 256, 0, stream>>>(buf1, attn_w, 1, xw3F, xTF, s1g, s2g);
    attn_fused_kernel<false><<<512, 256, 0, stream>>>(
        buf1, xbFb, xw3F, xTF, s1g, s2g, q1_len, q2_len, attn_b, 1, out, nullptr);
}